// Round 15
// baseline (122.598 us; speedup 1.0000x reference)
//
#include <hip/hip_runtime.h>
#include <hip/hip_bf16.h>
#include <cstddef>
#include <cstdint>

// SpatialPatchMoE on MI355X (gfx950).
// x[2,64,8,128,128] f32 -> 512 patches x 8 l-slices; router top-2/8;
// per expert: dwconv(1,7,7) -> LN(8,8) -> pw 64->128 -> silu*gate -> pw 64->64;
// out = x + sum_k w_k * expert_k.  Pointwise matmuls = bf16 MFMA 16x16x32.
//
// k_main round 15 = round 14 (fused two-expert pass, packed conv weights) with
// B3 eliminated: h_e1 carried in REGISTERS (hvb + mu1/rstd1) through e0's pw
// phases and written to B1 in phase 4.  LDS 49408 -> 40192 B = 4 blocks/CU
// (requires VGPR <= 64; r14 was 40).  Barriers 6 -> 7.
// k_pre fused into k_repack (extra blocks) to cut a launch gap.
//
// LDS carve (40192 B, 4 blocks/CU):
//   wsdw u32[49][64] (e0 lo | e1 hi) @0      (12544)
//   B1   u16 [64][72]    @12544  (9216)   h_e0 -> h_e1
//   B2   u16 [64][72]    @21760  (9216)   ln2 f32x2 (8192) -> h3_e0 -> h3_e1
//   xsb  u16 [64][72]    @30976  (9216)
//   eb   f32 [64][68]    @0      (17408)  epilogue alias over wsdw+B1
//
// ws layout (bytes):
//   partial_l : f32 [n][l][c]       @ 0         (1048576)
//   dwTbf     : bf16 [e][tap][c]    @ 1048576   (50176)
//   sel_i     : int[2*512]          @ 1098752   (4096)
//   sel_w     : f32[2*512]          @ 1102848   (4096)
//   wInBf     : bf16 [e][128][64]   @ 1106944   (131072)
//   wOutBf    : bf16 [e][64][64]    @ 1238016   (65536)
//   xr        : f32 [n*8+l][c][px]  @ 1303552   (67108864)   (repack path)

typedef __attribute__((ext_vector_type(8))) short short8;
typedef __attribute__((ext_vector_type(4))) float f32x4;
typedef __attribute__((ext_vector_type(2))) float f32x2;

#define REPACK_NEED 68412416ull

__device__ __forceinline__ unsigned short f2bf(float f) {
  return __builtin_bit_cast(unsigned short, __float2bfloat16(f));
}
__device__ __forceinline__ float bflo(unsigned u) {
  return __builtin_bit_cast(float, u << 16);
}
__device__ __forceinline__ float bfhi(unsigned u) {
  return __builtin_bit_cast(float, u & 0xFFFF0000u);
}

__device__ __forceinline__ float wave_sum64(float v) {
#pragma unroll
  for (int m = 32; m > 0; m >>= 1) v += __shfl_xor(v, m, 64);
  return v;
}

// ---------------- k_pre body (shared by standalone + fused-into-repack)
__device__ __forceinline__ void pre_body(int idx,
                                         const float* __restrict__ dw,
                                         const float* __restrict__ pwin,
                                         const float* __restrict__ pwout,
                                         unsigned short* __restrict__ dwTbf,
                                         unsigned short* __restrict__ wIn,
                                         unsigned short* __restrict__ wOut) {
  if (idx < 25088) {
    int e = idx / 3136;
    int r = idx - e * 3136;
    int c = r / 49;
    int tap = r - c * 49;
    dwTbf[(e * 49 + tap) * 64 + c] = f2bf(dw[idx]);
  } else if (idx < 25088 + 65536) {
    int i = idx - 25088;
    wIn[i] = f2bf(pwin[i]);
  } else if (idx < 25088 + 65536 + 32768) {
    int i = idx - 90624;
    wOut[i] = f2bf(pwout[i]);
  }
}

__global__ void k_pre(const float* __restrict__ dw,
                      const float* __restrict__ pwin,
                      const float* __restrict__ pwout,
                      unsigned short* __restrict__ dwTbf,
                      unsigned short* __restrict__ wIn,
                      unsigned short* __restrict__ wOut) {
  pre_body(blockIdx.x * 256 + threadIdx.x, dw, pwin, pwout, dwTbf, wIn, wOut);
}

// ---------------- fallback patch sums (only when ws too small for repack)
__global__ __launch_bounds__(256) void k_sum(const float* __restrict__ x,
                                             float* __restrict__ partial_l) {
  __shared__ float red[256 * 17];
  int t = threadIdx.x, bid = blockIdx.x;
  int b = bid >> 8, c = (bid >> 2) & 63, lp = bid & 3;
  const float4* x4 = (const float4*)x + ((size_t)((b * 64 + c) * 8) + lp * 2) * 4096;
#pragma unroll 1
  for (int l2 = 0; l2 < 2; ++l2) {
    float acc[16];
#pragma unroll
    for (int k = 0; k < 16; ++k) acc[k] = 0.f;
#pragma unroll
    for (int k = 0; k < 16; ++k) {
      float4 v = x4[l2 * 4096 + k * 256 + t];
      acc[k] += v.x + v.y + v.z + v.w;
    }
    int pcol = (t & 31) >> 1;
    int slot = ((t & 1) << 3) | (t >> 5);
    __syncthreads();
#pragma unroll
    for (int k = 0; k < 16; ++k) red[(k * 16 + pcol) * 17 + slot] = acc[k];
    __syncthreads();
    float s = 0.f;
#pragma unroll
    for (int j = 0; j < 16; ++j) s += red[t * 17 + j];
    partial_l[((size_t)(b * 256 + t)) * 512 + (lp * 2 + l2) * 64 + c] = s;
  }
}

// ---------------- repack x -> patch-major xr, fused patch sums + k_pre work
__global__ __launch_bounds__(256) void k_repack(
    const float* __restrict__ x, float* __restrict__ xr,
    float* __restrict__ partial_l,
    const float* __restrict__ dw, const float* __restrict__ pwin,
    const float* __restrict__ pwout, unsigned short* __restrict__ dwTbf,
    unsigned short* __restrict__ wIn, unsigned short* __restrict__ wOut) {
  int t = threadIdx.x, bid = blockIdx.x;
  if (bid >= 2048) {  // fused k_pre blocks
    pre_body((bid - 2048) * 256 + t, dw, pwin, pwout, dwTbf, wIn, wOut);
    return;
  }
  __shared__ __align__(16) float lt[8 * 1060];
  int ct = bid & 7, hh = (bid >> 3) & 15, l = (bid >> 7) & 7, b = bid >> 10;
  int c0 = ct * 8;
  const float4* x4 = (const float4*)x;
  float4* xr4 = (float4*)xr;
  int y = t >> 5, xq = t & 31;
#pragma unroll
  for (int i = 0; i < 8; ++i) {
    size_t src = ((size_t)((b * 64 + c0 + i) * 8 + l) << 12) +
                 (size_t)(hh * 8 + y) * 32 + xq;
    float4 v = x4[src];
    *(float4*)(lt + i * 1060 + y * 132 + xq * 4) = v;
  }
  __syncthreads();
  int cc = (t >> 4) & 7, ihalf = t >> 7, pxq = t & 15;
  int py = pxq >> 1, xcol = pxq & 1;
#pragma unroll
  for (int iw = 0; iw < 8; ++iw) {
    int ww = ihalf * 8 + iw;
    float4 v = *(const float4*)(lt + cc * 1060 + py * 132 + ww * 8 + xcol * 4);
    int n = b * 256 + hh * 16 + ww;
    xr4[((size_t)(n * 8 + l) << 10) + (c0 + cc) * 16 + pxq] = v;
    float s = v.x + v.y + v.z + v.w;
#pragma unroll
    for (int m = 1; m < 16; m <<= 1) s += __shfl_xor(s, m, 64);
    if (pxq == 0) partial_l[(size_t)(n * 8 + l) * 64 + c0 + cc] = s;
  }
}

// ---------------- router
__global__ void k_router(const float* __restrict__ partial_l,
                         const float* __restrict__ rw, const float* __restrict__ rb,
                         int* __restrict__ sel_i, float* __restrict__ sel_w) {
  int n = blockIdx.x;
  int lane = threadIdx.x;
  float s = 0.f;
#pragma unroll
  for (int l = 0; l < 8; ++l)
    s += partial_l[(size_t)n * 512 + l * 64 + lane];
  float rin = s * (1.f / 512.f);
  float lg[8];
#pragma unroll
  for (int e = 0; e < 8; ++e) {
    float v = rin * rw[e * 64 + lane];
    lg[e] = wave_sum64(v) + rb[e];
  }
  int e0 = 0; float v0 = lg[0];
#pragma unroll
  for (int e = 1; e < 8; ++e) if (lg[e] > v0) { v0 = lg[e]; e0 = e; }
  int e1 = -1; float v1 = -1e30f;
#pragma unroll
  for (int e = 0; e < 8; ++e) if (e != e0 && lg[e] > v1) { v1 = lg[e]; e1 = e; }
  if (lane == 0) {
    float w1 = __expf(v1 - v0);
    float z = 1.f + w1;
    sel_i[2 * n] = e0; sel_i[2 * n + 1] = e1;
    sel_w[2 * n] = 1.f / z; sel_w[2 * n + 1] = w1 / z;
  }
}

// ---------------- main: one block per (patch n, depth l); 8 waves of 64
template <bool REPACK>
__global__ __launch_bounds__(512) void k_main(
    const float* __restrict__ x, const float* __restrict__ xr,
    const unsigned short* __restrict__ dwTbf, const float* __restrict__ dwb,
    const float* __restrict__ lnw, const float* __restrict__ lnb,
    const float* __restrict__ pwin_b, const float* __restrict__ pwout_b,
    const unsigned short* __restrict__ wInBf,
    const unsigned short* __restrict__ wOutBf,
    const int* __restrict__ sel_i, const float* __restrict__ sel_w,
    float* __restrict__ out) {
  __shared__ __align__(16) char smem[40192];
  unsigned* wsdw       = (unsigned*)smem;                  // [49][64] u32 e0|e1
  unsigned short* B1   = (unsigned short*)(smem + 12544);  // h_e0 -> h_e1
  unsigned short* B2   = (unsigned short*)(smem + 21760);  // ln2 -> h3_e0 -> h3_e1
  f32x2* ln2           = (f32x2*)(smem + 21760);           // [2][8][64] f32x2
  unsigned short* xsb  = (unsigned short*)(smem + 30976);
  float* eb            = (float*)smem;                     // alias wsdw+B1

  const int t = threadIdx.x;
  const int lane = t & 63;
  const int wv = __builtin_amdgcn_readfirstlane(t >> 6);  // 0..7
  const int wi = wv >> 1;      // MFMA row-tile index 0..3
  const int jh = wv & 1;       // px-half 0..1
  const int r15 = lane & 15, r4 = lane >> 4;
  const int bidx = blockIdx.x;
  const int n = bidx >> 3, l = bidx & 7;
  const int b = n >> 8, p = n & 255;
  const int hh = p >> 4, ww = p & 15;
  const size_t obase = (size_t)b * 8388608 + (size_t)l * 16384 +
                       (size_t)hh * 1024 + (size_t)ww * 8;

  const int e0 = __builtin_amdgcn_readfirstlane(sel_i[2 * n]);
  const int e1 = __builtin_amdgcn_readfirstlane(sel_i[2 * n + 1]);
  const float we0 = sel_w[2 * n];
  const float we1 = sel_w[2 * n + 1];

  // ---- phase 0: stage x slice -> xsb bf16 (stride 72, XOR row swizzle) and
  //      both experts' dw weights packed u32 (lo = e0, hi = e1)
#pragma unroll
  for (int it = 0; it < 2; ++it) {
    int g = it * 512 + t;
    int c = g >> 4, q = g & 15;
    float4 v;
    if constexpr (REPACK)
      v = ((const float4*)xr)[(size_t)bidx * 1024 + g];
    else
      v = *(const float4*)(x + obase + (size_t)c * 131072 + (q >> 1) * 128 + (q & 1) * 4);
    int rs = (q >> 1) ^ ((c >> 3) & 7);
    uint2 w2;
    w2.x = (unsigned)f2bf(v.x) | ((unsigned)f2bf(v.y) << 16);
    w2.y = (unsigned)f2bf(v.z) | ((unsigned)f2bf(v.w) << 16);
    *(uint2*)(xsb + c * 72 + rs * 8 + (q & 1) * 4) = w2;
  }
  {
    const unsigned short* s0 = dwTbf + (size_t)e0 * 3136;
    const unsigned short* s1 = dwTbf + (size_t)e1 * 3136;
#pragma unroll
    for (int i = 0; i < 6; ++i) {
      int idx = i * 512 + t;
      wsdw[idx] = (unsigned)s0[idx] | ((unsigned)s1[idx] << 16);
    }
    if (t < 64) wsdw[3072 + t] = (unsigned)s0[3072 + t] | ((unsigned)s1[3072 + t] << 16);
  }
  __syncthreads();  // barrier A

  // ---- phase 1: conv BOTH experts; shared x unpack; wave wv owns row wv
  f32x2 hva[4], hvb[4];
  {
    const float bias0 = dwb[e0 * 64 + lane];
    const float bias1 = dwb[e1 * 64 + lane];
#pragma unroll
    for (int j = 0; j < 4; ++j) {
      hva[j] = f32x2{bias0, bias0};
      hvb[j] = f32x2{bias1, bias1};
    }
  }
  {
    const unsigned short* rowbase = xsb + lane * 72;
    const int rc = (lane >> 3) & 7;
    const unsigned* wl = wsdw + lane;
    const int y0 = wv;
    const int rlo = (y0 - 3 < 0) ? 0 : y0 - 3;
    const int rhi = (y0 + 3 > 7) ? 7 : y0 + 3;
    for (int r = rlo; r <= rhi; ++r) {   // runtime loop: small code, few regs
      uint4 xraw = *(const uint4*)(rowbase + (r ^ rc) * 8);
      float xp[14];
      xp[0] = 0.f; xp[1] = 0.f; xp[2] = 0.f;
      xp[3] = bflo(xraw.x); xp[4] = bfhi(xraw.x);
      xp[5] = bflo(xraw.y); xp[6] = bfhi(xraw.y);
      xp[7] = bflo(xraw.z); xp[8] = bfhi(xraw.z);
      xp[9] = bflo(xraw.w); xp[10] = bfhi(xraw.w);
      xp[11] = 0.f; xp[12] = 0.f; xp[13] = 0.f;
      f32x2 pr[13];
#pragma unroll
      for (int m = 0; m < 13; ++m) pr[m] = f32x2{xp[m], xp[m + 1]};
      const unsigned* wrow = wl + (r - y0 + 3) * 448;   // 7 taps * 64 u32
#pragma unroll
      for (int dx = 0; dx < 7; ++dx) {
        unsigned wp = wrow[dx * 64];        // one ds_read_b32, both experts
        float wt0 = bflo(wp);
        float wt1 = bfhi(wp);
        f32x2 w20 = f32x2{wt0, wt0};
        f32x2 w21 = f32x2{wt1, wt1};
        hva[0] = __builtin_elementwise_fma(pr[dx + 0], w20, hva[0]);
        hva[1] = __builtin_elementwise_fma(pr[dx + 2], w20, hva[1]);
        hva[2] = __builtin_elementwise_fma(pr[dx + 4], w20, hva[2]);
        hva[3] = __builtin_elementwise_fma(pr[dx + 6], w20, hva[3]);
        hvb[0] = __builtin_elementwise_fma(pr[dx + 0], w21, hvb[0]);
        hvb[1] = __builtin_elementwise_fma(pr[dx + 2], w21, hvb[1]);
        hvb[2] = __builtin_elementwise_fma(pr[dx + 4], w21, hvb[2]);
        hvb[3] = __builtin_elementwise_fma(pr[dx + 6], w21, hvb[3]);
      }
    }
  }
  // LN partials for both experts, packed f32x2 -> ln2 (aliases B2)
  {
    f32x2 psa = f32x2{0.f, 0.f}, pqa = f32x2{0.f, 0.f};
    f32x2 psb = f32x2{0.f, 0.f}, pqb = f32x2{0.f, 0.f};
#pragma unroll
    for (int j = 0; j < 4; ++j) {
      psa += hva[j];
      pqa = __builtin_elementwise_fma(hva[j], hva[j], pqa);
      psb += hvb[j];
      pqb = __builtin_elementwise_fma(hvb[j], hvb[j], pqb);
    }
    ln2[(0 * 8 + wv) * 64 + lane] = f32x2{psa.x + psa.y, pqa.x + pqa.y};
    ln2[(1 * 8 + wv) * 64 + lane] = f32x2{psb.x + psb.y, pqb.x + pqb.y};
  }
  __syncthreads();  // barrier B

  // ---- phase 2: LN finalize both; write B1 = h_e0 ONLY; h_e1 stays in regs
  float mu1, rstd1;
  {
    float sm0 = 0.f, sq0 = 0.f, sm1 = 0.f, sq1 = 0.f;
#pragma unroll
    for (int w = 0; w < 8; ++w) {
      f32x2 va = ln2[(0 * 8 + w) * 64 + lane];
      f32x2 vb = ln2[(1 * 8 + w) * 64 + lane];
      sm0 += va.x; sq0 += va.y;
      sm1 += vb.x; sq1 += vb.y;
    }
    float mu0 = sm0 * (1.f / 64.f);
    float rstd0 = rsqrtf(sq0 * (1.f / 64.f) - mu0 * mu0 + 1e-5f);
    mu1 = sm1 * (1.f / 64.f);
    rstd1 = rsqrtf(sq1 * (1.f / 64.f) - mu1 * mu1 + 1e-5f);
#pragma unroll
    for (int j = 0; j < 8; ++j) {
      int s = wv * 8 + j;
      float ha = (j & 1) ? hva[j >> 1].y : hva[j >> 1].x;
      float nv0 = (ha - mu0) * rstd0 * lnw[e0 * 64 + s] + lnb[e0 * 64 + s];
      B1[s * 72 + lane] = f2bf(nv0);
    }
  }
  __syncthreads();  // barrier C (ln2 reads done -> B2 reusable)

  float oacc[8];
#pragma unroll
  for (int i = 0; i < 8; ++i) oacc[i] = 0.f;

  // ---- phase 3: pw_in e0 (read B1) -> silu -> h3_e0 into B2
  {
    const unsigned short* wInE = wInBf + (size_t)e0 * 8192;
    short8 aA[2], aG[2];
#pragma unroll
    for (int kf = 0; kf < 2; ++kf) {
      aA[kf] = *(const short8*)(wInE + (16 * wi + r15) * 64 + kf * 32 + r4 * 8);
      aG[kf] = *(const short8*)(wInE + (64 + 16 * wi + r15) * 64 + kf * 32 + r4 * 8);
    }
    f32x4 accA[2], accG[2];
#pragma unroll
    for (int ntl = 0; ntl < 2; ++ntl)
#pragma unroll
      for (int v = 0; v < 4; ++v) {
        accA[ntl][v] = pwin_b[e0 * 128 + 16 * wi + r4 * 4 + v];
        accG[ntl][v] = pwin_b[e0 * 128 + 64 + 16 * wi + r4 * 4 + v];
      }
#pragma unroll
    for (int ntl = 0; ntl < 2; ++ntl) {
      const int nt = 2 * jh + ntl;
#pragma unroll
      for (int kf = 0; kf < 2; ++kf) {
        short8 bfr = *(const short8*)(B1 + (16 * nt + r15) * 72 + kf * 32 + r4 * 8);
        accA[ntl] = __builtin_amdgcn_mfma_f32_16x16x32_bf16(aA[kf], bfr, accA[ntl], 0, 0, 0);
        accG[ntl] = __builtin_amdgcn_mfma_f32_16x16x32_bf16(aG[kf], bfr, accG[ntl], 0, 0, 0);
      }
    }
#pragma unroll
    for (int ntl = 0; ntl < 2; ++ntl) {
      const int nt = 2 * jh + ntl;
      float hval[4];
#pragma unroll
      for (int v = 0; v < 4; ++v) {
        float a = accA[ntl][v];
        float g = accG[ntl][v];
        hval[v] = __fdividef(a, 1.f + __expf(-a)) * g;
      }
      uint2 w2;
      w2.x = (unsigned)f2bf(hval[0]) | ((unsigned)f2bf(hval[1]) << 16);
      w2.y = (unsigned)f2bf(hval[2]) | ((unsigned)f2bf(hval[3]) << 16);
      *(uint2*)(B2 + (16 * nt + r15) * 72 + 16 * wi + 4 * r4) = w2;
    }
  }
  __syncthreads();  // barrier D (h3_e0 ready; all B1 reads done)

  // ---- phase 4: pw_out e0 (read B2) -> oacc  ||  write B1 = h_e1 (from regs)
  {
#pragma unroll
    for (int j = 0; j < 8; ++j) {
      int s = wv * 8 + j;
      float hb = (j & 1) ? hvb[j >> 1].y : hvb[j >> 1].x;
      float nv1 = (hb - mu1) * rstd1 * lnw[e1 * 64 + s] + lnb[e1 * 64 + s];
      B1[s * 72 + lane] = f2bf(nv1);
    }
    const unsigned short* wOutE = wOutBf + (size_t)e0 * 4096;
    short8 aO[2];
#pragma unroll
    for (int kf = 0; kf < 2; ++kf)
      aO[kf] = *(const short8*)(wOutE + (16 * wi + r15) * 64 + kf * 32 + r4 * 8);
    f32x4 accO[2];
#pragma unroll
    for (int ntl = 0; ntl < 2; ++ntl)
#pragma unroll
      for (int v = 0; v < 4; ++v) accO[ntl][v] = 0.f;
#pragma unroll
    for (int ntl = 0; ntl < 2; ++ntl) {
      const int nt = 2 * jh + ntl;
#pragma unroll
      for (int kf = 0; kf < 2; ++kf) {
        short8 bfr = *(const short8*)(B2 + (16 * nt + r15) * 72 + kf * 32 + r4 * 8);
        accO[ntl] = __builtin_amdgcn_mfma_f32_16x16x32_bf16(aO[kf], bfr, accO[ntl], 0, 0, 0);
      }
    }
    float bO[4];
#pragma unroll
    for (int v = 0; v < 4; ++v) bO[v] = pwout_b[e0 * 64 + 16 * wi + r4 * 4 + v];
#pragma unroll
    for (int ntl = 0; ntl < 2; ++ntl)
#pragma unroll
      for (int v = 0; v < 4; ++v) oacc[ntl * 4 + v] += we0 * (accO[ntl][v] + bO[v]);
  }
  __syncthreads();  // barrier E (h_e1 ready; all B2(h3_e0) reads done)

  // ---- phase 5: pw_in e1 (read B1) -> silu -> h3_e1 into B2
  {
    const unsigned short* wInE = wInBf + (size_t)e1 * 8192;
    short8 aA[2], aG[2];
#pragma unroll
    for (int kf = 0; kf < 2; ++kf) {
      aA[kf] = *(const short8*)(wInE + (16 * wi + r15) * 64 + kf * 32 + r4 * 8);
      aG[kf] = *(const short8*)(wInE + (64 + 16 * wi + r15) * 64 + kf * 32 + r4 * 8);
    }
    f32x4 accA[2], accG[2];
#pragma unroll
    for (int ntl = 0; ntl < 2; ++ntl)
#pragma unroll
      for (int v = 0; v < 4; ++v) {
        accA[ntl][v] = pwin_b[e1 * 128 + 16 * wi + r4 * 4 + v];
        accG[ntl][v] = pwin_b[e1 * 128 + 64 + 16 * wi + r4 * 4 + v];
      }
#pragma unroll
    for (int ntl = 0; ntl < 2; ++ntl) {
      const int nt = 2 * jh + ntl;
#pragma unroll
      for (int kf = 0; kf < 2; ++kf) {
        short8 bfr = *(const short8*)(B1 + (16 * nt + r15) * 72 + kf * 32 + r4 * 8);
        accA[ntl] = __builtin_amdgcn_mfma_f32_16x16x32_bf16(aA[kf], bfr, accA[ntl], 0, 0, 0);
        accG[ntl] = __builtin_amdgcn_mfma_f32_16x16x32_bf16(aG[kf], bfr, accG[ntl], 0, 0, 0);
      }
    }
#pragma unroll
    for (int ntl = 0; ntl < 2; ++ntl) {
      const int nt = 2 * jh + ntl;
      float hval[4];
#pragma unroll
      for (int v = 0; v < 4; ++v) {
        float a = accA[ntl][v];
        float g = accG[ntl][v];
        hval[v] = __fdividef(a, 1.f + __expf(-a)) * g;
      }
      uint2 w2;
      w2.x = (unsigned)f2bf(hval[0]) | ((unsigned)f2bf(hval[1]) << 16);
      w2.y = (unsigned)f2bf(hval[2]) | ((unsigned)f2bf(hval[3]) << 16);
      *(uint2*)(B2 + (16 * nt + r15) * 72 + 16 * wi + 4 * r4) = w2;
    }
  }
  __syncthreads();  // barrier F (h3_e1 ready; all B1 reads done)

  // ---- phase 6: pw_out e1 (read B2) -> oacc; write eb (aliases wsdw+B1)
  {
    const unsigned short* wOutE = wOutBf + (size_t)e1 * 4096;
    short8 aO[2];
#pragma unroll
    for (int kf = 0; kf < 2; ++kf)
      aO[kf] = *(const short8*)(wOutE + (16 * wi + r15) * 64 + kf * 32 + r4 * 8);
    f32x4 accO[2];
#pragma unroll
    for (int ntl = 0; ntl < 2; ++ntl)
#pragma unroll
      for (int v = 0; v < 4; ++v) accO[ntl][v] = 0.f;
#pragma unroll
    for (int ntl = 0; ntl < 2; ++ntl) {
      const int nt = 2 * jh + ntl;
#pragma unroll
      for (int kf = 0; kf < 2; ++kf) {
        short8 bfr = *(const short8*)(B2 + (16 * nt + r15) * 72 + kf * 32 + r4 * 8);
        accO[ntl] = __builtin_amdgcn_mfma_f32_16x16x32_bf16(aO[kf], bfr, accO[ntl], 0, 0, 0);
      }
    }
    float bO[4];
#pragma unroll
    for (int v = 0; v < 4; ++v) bO[v] = pwout_b[e1 * 64 + 16 * wi + r4 * 4 + v];
#pragma unroll
    for (int ntl = 0; ntl < 2; ++ntl)
#pragma unroll
      for (int v = 0; v < 4; ++v) oacc[ntl * 4 + v] += we1 * (accO[ntl][v] + bO[v]);
  }
#pragma unroll
  for (int ntl = 0; ntl < 2; ++ntl)
#pragma unroll
    for (int v = 0; v < 4; ++v)
      eb[(16 * wi + 4 * r4 + v) * 68 + 16 * (2 * jh + ntl) + r15] = oacc[ntl * 4 + v];
  __syncthreads();  // barrier G

  // ---- epilogue: read eb, residual from global, store
#pragma unroll
  for (int it = 0; it < 2; ++it) {
    int g = it * 512 + t;
    int c = g >> 4, q = g & 15;
    float4 dv = *(const float4*)(eb + c * 68 + q * 4);
    float4 xv;   // residual from global (L2/L3-hot)
    if constexpr (REPACK)
      xv = ((const float4*)xr)[(size_t)bidx * 1024 + g];
    else
      xv = *(const float4*)(x + obase + (size_t)c * 131072 + (q >> 1) * 128 + (q & 1) * 4);
    float4 o4 = {xv.x + dv.x, xv.y + dv.y, xv.z + dv.z, xv.w + dv.w};
    *(float4*)(out + obase + (size_t)c * 131072 + (q >> 1) * 128 + (q & 1) * 4) = o4;
  }
}

extern "C" void kernel_launch(void* const* d_in, const int* in_sizes, int n_in,
                              void* d_out, int out_size, void* d_ws, size_t ws_size,
                              hipStream_t stream) {
  const float* x       = (const float*)d_in[0];
  const float* rw      = (const float*)d_in[1];
  const float* rb      = (const float*)d_in[2];
  const float* dww     = (const float*)d_in[3];
  const float* dwb     = (const float*)d_in[4];
  const float* lnw     = (const float*)d_in[5];
  const float* lnb     = (const float*)d_in[6];
  const float* pwin_w  = (const float*)d_in[7];
  const float* pwin_b  = (const float*)d_in[8];
  const float* pwout_w = (const float*)d_in[9];
  const float* pwout_b = (const float*)d_in[10];
  float* out = (float*)d_out;

  char* ws = (char*)d_ws;
  float*          partial_l = (float*)ws;
  unsigned short* dwTbf     = (unsigned short*)(ws + 1048576);
  int*            sel_i     = (int*)(ws + 1098752);
  float*          sel_w     = (float*)(ws + 1102848);
  unsigned short* wInBf     = (unsigned short*)(ws + 1106944);
  unsigned short* wOutBf    = (unsigned short*)(ws + 1238016);
  float*          xr        = (float*)(ws + 1303552);

  const bool repack = ws_size >= REPACK_NEED;

  if (repack) {
    // fused: blocks [0,2048) repack+sums, [2048,2544) weight preprocess
    hipLaunchKernelGGL(k_repack, dim3(2544), dim3(256), 0, stream,
                       x, xr, partial_l, dww, pwin_w, pwout_w, dwTbf, wInBf, wOutBf);
  } else {
    hipLaunchKernelGGL(k_pre, dim3(496), dim3(256), 0, stream,
                       dww, pwin_w, pwout_w, dwTbf, wInBf, wOutBf);
    hipLaunchKernelGGL(k_sum, dim3(512), dim3(256), 0, stream, x, partial_l);
  }
  hipLaunchKernelGGL(k_router, dim3(512), dim3(64), 0, stream,
                     partial_l, rw, rb, sel_i, sel_w);
  if (repack)
    hipLaunchKernelGGL((k_main<true>), dim3(4096), dim3(512), 0, stream,
                       x, xr, dwTbf, dwb, lnw, lnb, pwin_b, pwout_b,
                       wInBf, wOutBf, sel_i, sel_w, out);
  else
    hipLaunchKernelGGL((k_main<false>), dim3(4096), dim3(512), 0, stream,
                       x, xr, dwTbf, dwb, lnw, lnb, pwin_b, pwout_b,
                       wInBf, wOutBf, sel_i, sel_w, out);
}

// Round 16
// 108.253 us; speedup vs baseline: 1.1325x; 1.1325x over previous
//
#include <hip/hip_runtime.h>
#include <hip/hip_bf16.h>
#include <cstddef>
#include <cstdint>

// SpatialPatchMoE on MI355X (gfx950).
// x[2,64,8,128,128] f32 -> 512 patches x 8 l-slices; router top-2/8;
// per expert: dwconv(1,7,7) -> LN(8,8) -> pw 64->128 -> silu*gate -> pw 64->64;
// out = x + sum_k w_k * expert_k.  Pointwise matmuls = bf16 MFMA 16x16x32.
//
// k_main round 16 = round 14 VERBATIM (measured best: 93.5 us).  Round 15's
// B3-elimination (4 blocks/CU via extra barrier + reg-carried h_e1) REGRESSED:
// occupancy 57->41, VALUBusy 69->58 — barrier count/phase independence
// dominates residency.  Keep r15's fused k_pre-into-k_repack aux launch.
//
// LDS carve (49408 B, 3 blocks/CU):
//   wsdw u32[49][64] (e0 lo | e1 hi) @0      (12544)
//   B1   u16 [64][72]    @12544  (9216)   h_e0, later h3_e1
//   B2   u16 [64][72]    @21760  (9216)   h_e1, later eb head
//   B3   u16 [64][72]    @30976  (9216)   lnred f32x2 (8192) then h3_e0
//   xsb  u16 [64][72]    @40192  (9216)
//   eb   f32 [64][68]    @21760  (17408)  epilogue alias over B2+B3
//
// ws layout (bytes):
//   partial_l : f32 [n][l][c]       @ 0         (1048576)
//   dwTbf     : bf16 [e][tap][c]    @ 1048576   (50176)
//   sel_i     : int[2*512]          @ 1098752   (4096)
//   sel_w     : f32[2*512]          @ 1102848   (4096)
//   wInBf     : bf16 [e][128][64]   @ 1106944   (131072)
//   wOutBf    : bf16 [e][64][64]    @ 1238016   (65536)
//   xr        : f32 [n*8+l][c][px]  @ 1303552   (67108864)   (repack path)

typedef __attribute__((ext_vector_type(8))) short short8;
typedef __attribute__((ext_vector_type(4))) float f32x4;
typedef __attribute__((ext_vector_type(2))) float f32x2;

#define REPACK_NEED 68412416ull

__device__ __forceinline__ unsigned short f2bf(float f) {
  return __builtin_bit_cast(unsigned short, __float2bfloat16(f));
}
__device__ __forceinline__ float bflo(unsigned u) {
  return __builtin_bit_cast(float, u << 16);
}
__device__ __forceinline__ float bfhi(unsigned u) {
  return __builtin_bit_cast(float, u & 0xFFFF0000u);
}

__device__ __forceinline__ float wave_sum64(float v) {
#pragma unroll
  for (int m = 32; m > 0; m >>= 1) v += __shfl_xor(v, m, 64);
  return v;
}

// ---------------- k_pre body (shared by standalone + fused-into-repack)
__device__ __forceinline__ void pre_body(int idx,
                                         const float* __restrict__ dw,
                                         const float* __restrict__ pwin,
                                         const float* __restrict__ pwout,
                                         unsigned short* __restrict__ dwTbf,
                                         unsigned short* __restrict__ wIn,
                                         unsigned short* __restrict__ wOut) {
  if (idx < 25088) {
    int e = idx / 3136;
    int r = idx - e * 3136;
    int c = r / 49;
    int tap = r - c * 49;
    dwTbf[(e * 49 + tap) * 64 + c] = f2bf(dw[idx]);
  } else if (idx < 25088 + 65536) {
    int i = idx - 25088;
    wIn[i] = f2bf(pwin[i]);
  } else if (idx < 25088 + 65536 + 32768) {
    int i = idx - 90624;
    wOut[i] = f2bf(pwout[i]);
  }
}

__global__ void k_pre(const float* __restrict__ dw,
                      const float* __restrict__ pwin,
                      const float* __restrict__ pwout,
                      unsigned short* __restrict__ dwTbf,
                      unsigned short* __restrict__ wIn,
                      unsigned short* __restrict__ wOut) {
  pre_body(blockIdx.x * 256 + threadIdx.x, dw, pwin, pwout, dwTbf, wIn, wOut);
}

// ---------------- fallback patch sums (only when ws too small for repack)
__global__ __launch_bounds__(256) void k_sum(const float* __restrict__ x,
                                             float* __restrict__ partial_l) {
  __shared__ float red[256 * 17];
  int t = threadIdx.x, bid = blockIdx.x;
  int b = bid >> 8, c = (bid >> 2) & 63, lp = bid & 3;
  const float4* x4 = (const float4*)x + ((size_t)((b * 64 + c) * 8) + lp * 2) * 4096;
#pragma unroll 1
  for (int l2 = 0; l2 < 2; ++l2) {
    float acc[16];
#pragma unroll
    for (int k = 0; k < 16; ++k) acc[k] = 0.f;
#pragma unroll
    for (int k = 0; k < 16; ++k) {
      float4 v = x4[l2 * 4096 + k * 256 + t];
      acc[k] += v.x + v.y + v.z + v.w;
    }
    int pcol = (t & 31) >> 1;
    int slot = ((t & 1) << 3) | (t >> 5);
    __syncthreads();
#pragma unroll
    for (int k = 0; k < 16; ++k) red[(k * 16 + pcol) * 17 + slot] = acc[k];
    __syncthreads();
    float s = 0.f;
#pragma unroll
    for (int j = 0; j < 16; ++j) s += red[t * 17 + j];
    partial_l[((size_t)(b * 256 + t)) * 512 + (lp * 2 + l2) * 64 + c] = s;
  }
}

// ---------------- repack x -> patch-major xr, fused patch sums + k_pre work
__global__ __launch_bounds__(256) void k_repack(
    const float* __restrict__ x, float* __restrict__ xr,
    float* __restrict__ partial_l,
    const float* __restrict__ dw, const float* __restrict__ pwin,
    const float* __restrict__ pwout, unsigned short* __restrict__ dwTbf,
    unsigned short* __restrict__ wIn, unsigned short* __restrict__ wOut) {
  int t = threadIdx.x, bid = blockIdx.x;
  if (bid >= 2048) {  // fused k_pre blocks
    pre_body((bid - 2048) * 256 + t, dw, pwin, pwout, dwTbf, wIn, wOut);
    return;
  }
  __shared__ __align__(16) float lt[8 * 1060];
  int ct = bid & 7, hh = (bid >> 3) & 15, l = (bid >> 7) & 7, b = bid >> 10;
  int c0 = ct * 8;
  const float4* x4 = (const float4*)x;
  float4* xr4 = (float4*)xr;
  int y = t >> 5, xq = t & 31;
#pragma unroll
  for (int i = 0; i < 8; ++i) {
    size_t src = ((size_t)((b * 64 + c0 + i) * 8 + l) << 12) +
                 (size_t)(hh * 8 + y) * 32 + xq;
    float4 v = x4[src];
    *(float4*)(lt + i * 1060 + y * 132 + xq * 4) = v;
  }
  __syncthreads();
  int cc = (t >> 4) & 7, ihalf = t >> 7, pxq = t & 15;
  int py = pxq >> 1, xcol = pxq & 1;
#pragma unroll
  for (int iw = 0; iw < 8; ++iw) {
    int ww = ihalf * 8 + iw;
    float4 v = *(const float4*)(lt + cc * 1060 + py * 132 + ww * 8 + xcol * 4);
    int n = b * 256 + hh * 16 + ww;
    xr4[((size_t)(n * 8 + l) << 10) + (c0 + cc) * 16 + pxq] = v;
    float s = v.x + v.y + v.z + v.w;
#pragma unroll
    for (int m = 1; m < 16; m <<= 1) s += __shfl_xor(s, m, 64);
    if (pxq == 0) partial_l[(size_t)(n * 8 + l) * 64 + c0 + cc] = s;
  }
}

// ---------------- router
__global__ void k_router(const float* __restrict__ partial_l,
                         const float* __restrict__ rw, const float* __restrict__ rb,
                         int* __restrict__ sel_i, float* __restrict__ sel_w) {
  int n = blockIdx.x;
  int lane = threadIdx.x;
  float s = 0.f;
#pragma unroll
  for (int l = 0; l < 8; ++l)
    s += partial_l[(size_t)n * 512 + l * 64 + lane];
  float rin = s * (1.f / 512.f);
  float lg[8];
#pragma unroll
  for (int e = 0; e < 8; ++e) {
    float v = rin * rw[e * 64 + lane];
    lg[e] = wave_sum64(v) + rb[e];
  }
  int e0 = 0; float v0 = lg[0];
#pragma unroll
  for (int e = 1; e < 8; ++e) if (lg[e] > v0) { v0 = lg[e]; e0 = e; }
  int e1 = -1; float v1 = -1e30f;
#pragma unroll
  for (int e = 0; e < 8; ++e) if (e != e0 && lg[e] > v1) { v1 = lg[e]; e1 = e; }
  if (lane == 0) {
    float w1 = __expf(v1 - v0);
    float z = 1.f + w1;
    sel_i[2 * n] = e0; sel_i[2 * n + 1] = e1;
    sel_w[2 * n] = 1.f / z; sel_w[2 * n + 1] = w1 / z;
  }
}

// ---------------- main: one block per (patch n, depth l); 8 waves of 64
template <bool REPACK>
__global__ __launch_bounds__(512) void k_main(
    const float* __restrict__ x, const float* __restrict__ xr,
    const unsigned short* __restrict__ dwTbf, const float* __restrict__ dwb,
    const float* __restrict__ lnw, const float* __restrict__ lnb,
    const float* __restrict__ pwin_b, const float* __restrict__ pwout_b,
    const unsigned short* __restrict__ wInBf,
    const unsigned short* __restrict__ wOutBf,
    const int* __restrict__ sel_i, const float* __restrict__ sel_w,
    float* __restrict__ out) {
  __shared__ __align__(16) char smem[49408];
  unsigned* wsdw       = (unsigned*)smem;                  // [49][64] u32 e0|e1
  unsigned short* B1   = (unsigned short*)(smem + 12544);  // h_e0 -> h3_e1
  unsigned short* B2   = (unsigned short*)(smem + 21760);  // h_e1 -> (eb head)
  unsigned short* B3   = (unsigned short*)(smem + 30976);  // lnred -> h3_e0
  f32x2* ln2           = (f32x2*)(smem + 30976);           // [2][8][64] f32x2
  unsigned short* xsb  = (unsigned short*)(smem + 40192);
  float* eb            = (float*)(smem + 21760);           // alias B2+B3

  const int t = threadIdx.x;
  const int lane = t & 63;
  const int wv = __builtin_amdgcn_readfirstlane(t >> 6);  // 0..7
  const int wi = wv >> 1;      // MFMA row-tile index 0..3
  const int jh = wv & 1;       // px-half 0..1
  const int r15 = lane & 15, r4 = lane >> 4;
  const int bidx = blockIdx.x;
  const int n = bidx >> 3, l = bidx & 7;
  const int b = n >> 8, p = n & 255;
  const int hh = p >> 4, ww = p & 15;
  const size_t obase = (size_t)b * 8388608 + (size_t)l * 16384 +
                       (size_t)hh * 1024 + (size_t)ww * 8;

  const int e0 = __builtin_amdgcn_readfirstlane(sel_i[2 * n]);
  const int e1 = __builtin_amdgcn_readfirstlane(sel_i[2 * n + 1]);
  const float we0 = sel_w[2 * n];
  const float we1 = sel_w[2 * n + 1];

  // ---- phase 0: stage x slice -> xsb bf16 (stride 72, XOR row swizzle) and
  //      both experts' dw weights packed u32 (lo = e0, hi = e1)
#pragma unroll
  for (int it = 0; it < 2; ++it) {
    int g = it * 512 + t;
    int c = g >> 4, q = g & 15;
    float4 v;
    if constexpr (REPACK)
      v = ((const float4*)xr)[(size_t)bidx * 1024 + g];
    else
      v = *(const float4*)(x + obase + (size_t)c * 131072 + (q >> 1) * 128 + (q & 1) * 4);
    int rs = (q >> 1) ^ ((c >> 3) & 7);
    uint2 w2;
    w2.x = (unsigned)f2bf(v.x) | ((unsigned)f2bf(v.y) << 16);
    w2.y = (unsigned)f2bf(v.z) | ((unsigned)f2bf(v.w) << 16);
    *(uint2*)(xsb + c * 72 + rs * 8 + (q & 1) * 4) = w2;
  }
  {
    const unsigned short* s0 = dwTbf + (size_t)e0 * 3136;
    const unsigned short* s1 = dwTbf + (size_t)e1 * 3136;
#pragma unroll
    for (int i = 0; i < 6; ++i) {
      int idx = i * 512 + t;
      wsdw[idx] = (unsigned)s0[idx] | ((unsigned)s1[idx] << 16);
    }
    if (t < 64) wsdw[3072 + t] = (unsigned)s0[3072 + t] | ((unsigned)s1[3072 + t] << 16);
  }
  __syncthreads();  // barrier A

  // ---- phase 1: conv BOTH experts; shared x unpack; wave wv owns row wv
  f32x2 hva[4], hvb[4];
  {
    const float bias0 = dwb[e0 * 64 + lane];
    const float bias1 = dwb[e1 * 64 + lane];
#pragma unroll
    for (int j = 0; j < 4; ++j) {
      hva[j] = f32x2{bias0, bias0};
      hvb[j] = f32x2{bias1, bias1};
    }
  }
  {
    const unsigned short* rowbase = xsb + lane * 72;
    const int rc = (lane >> 3) & 7;
    const unsigned* wl = wsdw + lane;
    const int y0 = wv;
    const int rlo = (y0 - 3 < 0) ? 0 : y0 - 3;
    const int rhi = (y0 + 3 > 7) ? 7 : y0 + 3;
    for (int r = rlo; r <= rhi; ++r) {   // runtime loop: small code, few regs
      uint4 xraw = *(const uint4*)(rowbase + (r ^ rc) * 8);
      float xp[14];
      xp[0] = 0.f; xp[1] = 0.f; xp[2] = 0.f;
      xp[3] = bflo(xraw.x); xp[4] = bfhi(xraw.x);
      xp[5] = bflo(xraw.y); xp[6] = bfhi(xraw.y);
      xp[7] = bflo(xraw.z); xp[8] = bfhi(xraw.z);
      xp[9] = bflo(xraw.w); xp[10] = bfhi(xraw.w);
      xp[11] = 0.f; xp[12] = 0.f; xp[13] = 0.f;
      f32x2 pr[13];
#pragma unroll
      for (int m = 0; m < 13; ++m) pr[m] = f32x2{xp[m], xp[m + 1]};
      const unsigned* wrow = wl + (r - y0 + 3) * 448;   // 7 taps * 64 u32
#pragma unroll
      for (int dx = 0; dx < 7; ++dx) {
        unsigned wp = wrow[dx * 64];        // one ds_read_b32, both experts
        float wt0 = bflo(wp);
        float wt1 = bfhi(wp);
        f32x2 w20 = f32x2{wt0, wt0};
        f32x2 w21 = f32x2{wt1, wt1};
        hva[0] = __builtin_elementwise_fma(pr[dx + 0], w20, hva[0]);
        hva[1] = __builtin_elementwise_fma(pr[dx + 2], w20, hva[1]);
        hva[2] = __builtin_elementwise_fma(pr[dx + 4], w20, hva[2]);
        hva[3] = __builtin_elementwise_fma(pr[dx + 6], w20, hva[3]);
        hvb[0] = __builtin_elementwise_fma(pr[dx + 0], w21, hvb[0]);
        hvb[1] = __builtin_elementwise_fma(pr[dx + 2], w21, hvb[1]);
        hvb[2] = __builtin_elementwise_fma(pr[dx + 4], w21, hvb[2]);
        hvb[3] = __builtin_elementwise_fma(pr[dx + 6], w21, hvb[3]);
      }
    }
  }
  // LN partials for both experts, packed f32x2 -> ln2 (aliases B3)
  {
    f32x2 psa = f32x2{0.f, 0.f}, pqa = f32x2{0.f, 0.f};
    f32x2 psb = f32x2{0.f, 0.f}, pqb = f32x2{0.f, 0.f};
#pragma unroll
    for (int j = 0; j < 4; ++j) {
      psa += hva[j];
      pqa = __builtin_elementwise_fma(hva[j], hva[j], pqa);
      psb += hvb[j];
      pqb = __builtin_elementwise_fma(hvb[j], hvb[j], pqb);
    }
    ln2[(0 * 8 + wv) * 64 + lane] = f32x2{psa.x + psa.y, pqa.x + pqa.y};
    ln2[(1 * 8 + wv) * 64 + lane] = f32x2{psb.x + psb.y, pqb.x + pqb.y};
  }
  __syncthreads();  // barrier B

  // ---- phase 2: LN finalize both; h_e0 -> B1, h_e1 -> B2
  {
    float sm0 = 0.f, sq0 = 0.f, sm1 = 0.f, sq1 = 0.f;
#pragma unroll
    for (int w = 0; w < 8; ++w) {
      f32x2 va = ln2[(0 * 8 + w) * 64 + lane];
      f32x2 vb = ln2[(1 * 8 + w) * 64 + lane];
      sm0 += va.x; sq0 += va.y;
      sm1 += vb.x; sq1 += vb.y;
    }
    float mu0 = sm0 * (1.f / 64.f);
    float rstd0 = rsqrtf(sq0 * (1.f / 64.f) - mu0 * mu0 + 1e-5f);
    float mu1 = sm1 * (1.f / 64.f);
    float rstd1 = rsqrtf(sq1 * (1.f / 64.f) - mu1 * mu1 + 1e-5f);
#pragma unroll
    for (int j = 0; j < 8; ++j) {
      int s = wv * 8 + j;
      float ha = (j & 1) ? hva[j >> 1].y : hva[j >> 1].x;
      float hb = (j & 1) ? hvb[j >> 1].y : hvb[j >> 1].x;
      float nv0 = (ha - mu0) * rstd0 * lnw[e0 * 64 + s] + lnb[e0 * 64 + s];
      float nv1 = (hb - mu1) * rstd1 * lnw[e1 * 64 + s] + lnb[e1 * 64 + s];
      B1[s * 72 + lane] = f2bf(nv0);
      B2[s * 72 + lane] = f2bf(nv1);
    }
  }
  __syncthreads();  // barrier C (ln2 reads done before B3 reused)

  float oacc[8];
#pragma unroll
  for (int i = 0; i < 8; ++i) oacc[i] = 0.f;

  // ---- phase 3: pw_in e0 (read B1) -> silu -> h3_e0 into B3
  {
    const unsigned short* wInE = wInBf + (size_t)e0 * 8192;
    short8 aA[2], aG[2];
#pragma unroll
    for (int kf = 0; kf < 2; ++kf) {
      aA[kf] = *(const short8*)(wInE + (16 * wi + r15) * 64 + kf * 32 + r4 * 8);
      aG[kf] = *(const short8*)(wInE + (64 + 16 * wi + r15) * 64 + kf * 32 + r4 * 8);
    }
    f32x4 accA[2], accG[2];
#pragma unroll
    for (int ntl = 0; ntl < 2; ++ntl)
#pragma unroll
      for (int v = 0; v < 4; ++v) {
        accA[ntl][v] = pwin_b[e0 * 128 + 16 * wi + r4 * 4 + v];
        accG[ntl][v] = pwin_b[e0 * 128 + 64 + 16 * wi + r4 * 4 + v];
      }
#pragma unroll
    for (int ntl = 0; ntl < 2; ++ntl) {
      const int nt = 2 * jh + ntl;
#pragma unroll
      for (int kf = 0; kf < 2; ++kf) {
        short8 bfr = *(const short8*)(B1 + (16 * nt + r15) * 72 + kf * 32 + r4 * 8);
        accA[ntl] = __builtin_amdgcn_mfma_f32_16x16x32_bf16(aA[kf], bfr, accA[ntl], 0, 0, 0);
        accG[ntl] = __builtin_amdgcn_mfma_f32_16x16x32_bf16(aG[kf], bfr, accG[ntl], 0, 0, 0);
      }
    }
#pragma unroll
    for (int ntl = 0; ntl < 2; ++ntl) {
      const int nt = 2 * jh + ntl;
      float hval[4];
#pragma unroll
      for (int v = 0; v < 4; ++v) {
        float a = accA[ntl][v];
        float g = accG[ntl][v];
        hval[v] = __fdividef(a, 1.f + __expf(-a)) * g;
      }
      uint2 w2;
      w2.x = (unsigned)f2bf(hval[0]) | ((unsigned)f2bf(hval[1]) << 16);
      w2.y = (unsigned)f2bf(hval[2]) | ((unsigned)f2bf(hval[3]) << 16);
      *(uint2*)(B3 + (16 * nt + r15) * 72 + 16 * wi + 4 * r4) = w2;
    }
  }
  __syncthreads();  // barrier D (h3_e0 ready; all B1 reads done)

  // ---- phase 4: pw_out e0 (read B3) -> oacc  ||  pw_in e1 (read B2) -> B1
  {
    const unsigned short* wOutE = wOutBf + (size_t)e0 * 4096;
    short8 aO[2];
#pragma unroll
    for (int kf = 0; kf < 2; ++kf)
      aO[kf] = *(const short8*)(wOutE + (16 * wi + r15) * 64 + kf * 32 + r4 * 8);
    f32x4 accO[2];
#pragma unroll
    for (int ntl = 0; ntl < 2; ++ntl)
#pragma unroll
      for (int v = 0; v < 4; ++v) accO[ntl][v] = 0.f;
#pragma unroll
    for (int ntl = 0; ntl < 2; ++ntl) {
      const int nt = 2 * jh + ntl;
#pragma unroll
      for (int kf = 0; kf < 2; ++kf) {
        short8 bfr = *(const short8*)(B3 + (16 * nt + r15) * 72 + kf * 32 + r4 * 8);
        accO[ntl] = __builtin_amdgcn_mfma_f32_16x16x32_bf16(aO[kf], bfr, accO[ntl], 0, 0, 0);
      }
    }
    float bO[4];
#pragma unroll
    for (int v = 0; v < 4; ++v) bO[v] = pwout_b[e0 * 64 + 16 * wi + r4 * 4 + v];
#pragma unroll
    for (int ntl = 0; ntl < 2; ++ntl)
#pragma unroll
      for (int v = 0; v < 4; ++v) oacc[ntl * 4 + v] += we0 * (accO[ntl][v] + bO[v]);

    // pw_in e1
    const unsigned short* wInE = wInBf + (size_t)e1 * 8192;
    short8 aA[2], aG[2];
#pragma unroll
    for (int kf = 0; kf < 2; ++kf) {
      aA[kf] = *(const short8*)(wInE + (16 * wi + r15) * 64 + kf * 32 + r4 * 8);
      aG[kf] = *(const short8*)(wInE + (64 + 16 * wi + r15) * 64 + kf * 32 + r4 * 8);
    }
    f32x4 accA[2], accG[2];
#pragma unroll
    for (int ntl = 0; ntl < 2; ++ntl)
#pragma unroll
      for (int v = 0; v < 4; ++v) {
        accA[ntl][v] = pwin_b[e1 * 128 + 16 * wi + r4 * 4 + v];
        accG[ntl][v] = pwin_b[e1 * 128 + 64 + 16 * wi + r4 * 4 + v];
      }
#pragma unroll
    for (int ntl = 0; ntl < 2; ++ntl) {
      const int nt = 2 * jh + ntl;
#pragma unroll
      for (int kf = 0; kf < 2; ++kf) {
        short8 bfr = *(const short8*)(B2 + (16 * nt + r15) * 72 + kf * 32 + r4 * 8);
        accA[ntl] = __builtin_amdgcn_mfma_f32_16x16x32_bf16(aA[kf], bfr, accA[ntl], 0, 0, 0);
        accG[ntl] = __builtin_amdgcn_mfma_f32_16x16x32_bf16(aG[kf], bfr, accG[ntl], 0, 0, 0);
      }
    }
#pragma unroll
    for (int ntl = 0; ntl < 2; ++ntl) {
      const int nt = 2 * jh + ntl;
      float hval[4];
#pragma unroll
      for (int v = 0; v < 4; ++v) {
        float a = accA[ntl][v];
        float g = accG[ntl][v];
        hval[v] = __fdividef(a, 1.f + __expf(-a)) * g;
      }
      uint2 w2;
      w2.x = (unsigned)f2bf(hval[0]) | ((unsigned)f2bf(hval[1]) << 16);
      w2.y = (unsigned)f2bf(hval[2]) | ((unsigned)f2bf(hval[3]) << 16);
      *(uint2*)(B1 + (16 * nt + r15) * 72 + 16 * wi + 4 * r4) = w2;  // h3_e1
    }
  }
  __syncthreads();  // barrier E (h3_e1 ready; B2/B3 reads done -> eb writable)

  // ---- phase 5: pw_out e1 (read B1) -> oacc; write eb (aliases B2+B3)
  {
    const unsigned short* wOutE = wOutBf + (size_t)e1 * 4096;
    short8 aO[2];
#pragma unroll
    for (int kf = 0; kf < 2; ++kf)
      aO[kf] = *(const short8*)(wOutE + (16 * wi + r15) * 64 + kf * 32 + r4 * 8);
    f32x4 accO[2];
#pragma unroll
    for (int ntl = 0; ntl < 2; ++ntl)
#pragma unroll
      for (int v = 0; v < 4; ++v) accO[ntl][v] = 0.f;
#pragma unroll
    for (int ntl = 0; ntl < 2; ++ntl) {
      const int nt = 2 * jh + ntl;
#pragma unroll
      for (int kf = 0; kf < 2; ++kf) {
        short8 bfr = *(const short8*)(B1 + (16 * nt + r15) * 72 + kf * 32 + r4 * 8);
        accO[ntl] = __builtin_amdgcn_mfma_f32_16x16x32_bf16(aO[kf], bfr, accO[ntl], 0, 0, 0);
      }
    }
    float bO[4];
#pragma unroll
    for (int v = 0; v < 4; ++v) bO[v] = pwout_b[e1 * 64 + 16 * wi + r4 * 4 + v];
#pragma unroll
    for (int ntl = 0; ntl < 2; ++ntl)
#pragma unroll
      for (int v = 0; v < 4; ++v) oacc[ntl * 4 + v] += we1 * (accO[ntl][v] + bO[v]);
  }
#pragma unroll
  for (int ntl = 0; ntl < 2; ++ntl)
#pragma unroll
    for (int v = 0; v < 4; ++v)
      eb[(16 * wi + 4 * r4 + v) * 68 + 16 * (2 * jh + ntl) + r15] = oacc[ntl * 4 + v];
  __syncthreads();  // barrier F

  // ---- epilogue: read eb, residual from global, store
#pragma unroll
  for (int it = 0; it < 2; ++it) {
    int g = it * 512 + t;
    int c = g >> 4, q = g & 15;
    float4 dv = *(const float4*)(eb + c * 68 + q * 4);
    float4 xv;   // residual from global (L2/L3-hot)
    if constexpr (REPACK)
      xv = ((const float4*)xr)[(size_t)bidx * 1024 + g];
    else
      xv = *(const float4*)(x + obase + (size_t)c * 131072 + (q >> 1) * 128 + (q & 1) * 4);
    float4 o4 = {xv.x + dv.x, xv.y + dv.y, xv.z + dv.z, xv.w + dv.w};
    *(float4*)(out + obase + (size_t)c * 131072 + (q >> 1) * 128 + (q & 1) * 4) = o4;
  }
}

extern "C" void kernel_launch(void* const* d_in, const int* in_sizes, int n_in,
                              void* d_out, int out_size, void* d_ws, size_t ws_size,
                              hipStream_t stream) {
  const float* x       = (const float*)d_in[0];
  const float* rw      = (const float*)d_in[1];
  const float* rb      = (const float*)d_in[2];
  const float* dww     = (const float*)d_in[3];
  const float* dwb     = (const float*)d_in[4];
  const float* lnw     = (const float*)d_in[5];
  const float* lnb     = (const float*)d_in[6];
  const float* pwin_w  = (const float*)d_in[7];
  const float* pwin_b  = (const float*)d_in[8];
  const float* pwout_w = (const float*)d_in[9];
  const float* pwout_b = (const float*)d_in[10];
  float* out = (float*)d_out;

  char* ws = (char*)d_ws;
  float*          partial_l = (float*)ws;
  unsigned short* dwTbf     = (unsigned short*)(ws + 1048576);
  int*            sel_i     = (int*)(ws + 1098752);
  float*          sel_w     = (float*)(ws + 1102848);
  unsigned short* wInBf     = (unsigned short*)(ws + 1106944);
  unsigned short* wOutBf    = (unsigned short*)(ws + 1238016);
  float*          xr        = (float*)(ws + 1303552);

  const bool repack = ws_size >= REPACK_NEED;

  if (repack) {
    // fused: blocks [0,2048) repack+sums, [2048,2544) weight preprocess
    hipLaunchKernelGGL(k_repack, dim3(2544), dim3(256), 0, stream,
                       x, xr, partial_l, dww, pwin_w, pwout_w, dwTbf, wInBf, wOutBf);
  } else {
    hipLaunchKernelGGL(k_pre, dim3(496), dim3(256), 0, stream,
                       dww, pwin_w, pwout_w, dwTbf, wInBf, wOutBf);
    hipLaunchKernelGGL(k_sum, dim3(512), dim3(256), 0, stream, x, partial_l);
  }
  hipLaunchKernelGGL(k_router, dim3(512), dim3(64), 0, stream,
                     partial_l, rw, rb, sel_i, sel_w);
  if (repack)
    hipLaunchKernelGGL((k_main<true>), dim3(4096), dim3(512), 0, stream,
                       x, xr, dwTbf, dwb, lnw, lnb, pwin_b, pwout_b,
                       wInBf, wOutBf, sel_i, sel_w, out);
  else
    hipLaunchKernelGGL((k_main<false>), dim3(4096), dim3(512), 0, stream,
                       x, xr, dwTbf, dwb, lnw, lnb, pwin_b, pwout_b,
                       wInBf, wOutBf, sel_i, sel_w, out);
}